// Round 2
// baseline (1670.043 us; speedup 1.0000x reference)
//
#include <hip/hip_runtime.h>
#include <stdint.h>
#include <stddef.h>

#define N_ROWS 65536
#define DIM 1024

typedef __bf16 bf16_t;
typedef __bf16 bf16x8 __attribute__((ext_vector_type(8)));
typedef float  f32x4  __attribute__((ext_vector_type(4)));

__device__ __forceinline__ void gload_lds16(const void* gp, void* lp) {
    __builtin_amdgcn_global_load_lds(
        (const __attribute__((address_space(1))) void*)gp,
        (__attribute__((address_space(3))) void*)lp,
        16, 0, 0);
}

// ---------------- small kernels ----------------

// route[i] = max(argmax(x_angle[i]), argmax(y_angle[i])), first-occurrence argmax
__global__ void route_kernel(const float* __restrict__ xa,
                             const float* __restrict__ ya,
                             int* __restrict__ route) {
    int i = blockIdx.x * blockDim.x + threadIdx.x;
    float x0 = xa[3 * i], x1 = xa[3 * i + 1], x2 = xa[3 * i + 2];
    int lx = 0; float vx = x0;
    if (x1 > vx) { vx = x1; lx = 1; }
    if (x2 > vx) { vx = x2; lx = 2; }
    float y0 = ya[3 * i], y1 = ya[3 * i + 1], y2 = ya[3 * i + 2];
    int ly = 0; float vy = y0;
    if (y1 > vy) { vy = y1; ly = 1; }
    if (y2 > vy) { vy = y2; ly = 2; }
    route[i] = lx > ly ? lx : ly;
}

__global__ void cvt_f32_bf16(const float* __restrict__ in, bf16_t* __restrict__ out) {
    size_t i = (size_t)(blockIdx.x * blockDim.x + threadIdx.x) * 8;
    f32x4 a = *(const f32x4*)(in + i);
    f32x4 b = *(const f32x4*)(in + i + 4);
    bf16x8 v;
    v[0] = (bf16_t)a[0]; v[1] = (bf16_t)a[1]; v[2] = (bf16_t)a[2]; v[3] = (bf16_t)a[3];
    v[4] = (bf16_t)b[0]; v[5] = (bf16_t)b[1]; v[6] = (bf16_t)b[2]; v[7] = (bf16_t)b[3];
    *(bf16x8*)(out + i) = v;
}

// ---------------- GEMM: C = A @ W^T + b, M=65536, N=K=1024 ----------------
// AMODE: 0 = A is bf16;  1 = A is f32 (convert during reg-staging)
// OUTMODE: 0 = write bf16
//          1 = write f32, passthrough x_feat where route==0  (final layer)
//          2 = write bf16, replace with bf16(x_feat) where route!=2  (Z-build fused)
template<int AMODE, int OUTMODE>
__global__ __launch_bounds__(256)
void gemm_bt(const void* __restrict__ Aptr,
             const bf16_t* __restrict__ Bw,     // [1024][1024] bf16, row n holds W[n][k]
             const float* __restrict__ bias,    // [1024] f32
             void* __restrict__ Cptr,
             const int* __restrict__ route,
             const float* __restrict__ xfeat) {
    __shared__ __align__(16) bf16_t sA[128 * 64];
    __shared__ __align__(16) bf16_t sB[128 * 64];

    const int t    = threadIdx.x;
    const int lane = t & 63;
    const int wave = t >> 6;
    const int wr   = wave >> 1;   // 2x2 wave grid, each wave owns 64x64
    const int wc   = wave & 1;

    const int bn = blockIdx.x & 7;     // N/128 = 8 column blocks (fastest-varying: A-tile L2 reuse)
    const int bm = blockIdx.x >> 3;
    const int m0 = bm * 128;
    const int n0 = bn * 128;

    f32x4 acc[4][4] = {};

    const bf16_t* Ab = (const bf16_t*)Aptr;
    const float*  Af = (const float*)Aptr;

    for (int kt = 0; kt < DIM / 64; ++kt) {
        const int kk = kt * 64;
        // ---- stage A tile (128 x 64) ----
        if constexpr (AMODE == 0) {
#pragma unroll
            for (int i = 0; i < 4; ++i) {
                const int L = i * 256 + t;         // 0..1023 lane-linear
                const int row = L >> 3, seg = L & 7;
                gload_lds16(Ab + (size_t)(m0 + row) * DIM + kk + seg * 8,
                            (char*)sA + (size_t)L * 16);
            }
        } else {
#pragma unroll
            for (int i = 0; i < 4; ++i) {
                const int L = i * 256 + t;
                const int row = L >> 3, seg = L & 7;
                const float* g = Af + (size_t)(m0 + row) * DIM + kk + seg * 8;
                f32x4 a = *(const f32x4*)g;
                f32x4 b = *(const f32x4*)(g + 4);
                bf16x8 v;
                v[0] = (bf16_t)a[0]; v[1] = (bf16_t)a[1]; v[2] = (bf16_t)a[2]; v[3] = (bf16_t)a[3];
                v[4] = (bf16_t)b[0]; v[5] = (bf16_t)b[1]; v[6] = (bf16_t)b[2]; v[7] = (bf16_t)b[3];
                *(bf16x8*)((char*)sA + (size_t)L * 16) = v;
            }
        }
        // ---- stage B tile (W rows n0..n0+127, k kk..kk+63) ----
#pragma unroll
        for (int i = 0; i < 4; ++i) {
            const int L = i * 256 + t;
            const int row = L >> 3, seg = L & 7;
            gload_lds16(Bw + (size_t)(n0 + row) * DIM + kk + seg * 8,
                        (char*)sB + (size_t)L * 16);
        }
        __syncthreads();
        // ---- compute: 2 k-slices of 32, 16 MFMA each ----
#pragma unroll
        for (int ks = 0; ks < 2; ++ks) {
            bf16x8 afr[4], bfr[4];
#pragma unroll
            for (int m = 0; m < 4; ++m)
                afr[m] = *(const bf16x8*)(sA + (size_t)(wr * 64 + m * 16 + (lane & 15)) * 64
                                              + ks * 32 + (lane >> 4) * 8);
#pragma unroll
            for (int n = 0; n < 4; ++n)
                bfr[n] = *(const bf16x8*)(sB + (size_t)(wc * 64 + n * 16 + (lane & 15)) * 64
                                              + ks * 32 + (lane >> 4) * 8);
#pragma unroll
            for (int m = 0; m < 4; ++m)
#pragma unroll
                for (int n = 0; n < 4; ++n)
                    acc[m][n] = __builtin_amdgcn_mfma_f32_16x16x32_bf16(afr[m], bfr[n], acc[m][n], 0, 0, 0);
        }
        __syncthreads();
    }

    // ---- epilogue: D row=(lane>>4)*4+reg (M), col=lane&15 (N)  [m89-verified] ----
    const int cf = lane & 15;
#pragma unroll
    for (int m = 0; m < 4; ++m) {
        const int rowf = m0 + wr * 64 + m * 16 + (lane >> 4) * 4;
#pragma unroll
        for (int n = 0; n < 4; ++n) {
            const int colg = n0 + wc * 64 + n * 16 + cf;
            const float bv = bias[colg];
#pragma unroll
            for (int r = 0; r < 4; ++r) {
                const int rowg = rowf + r;
                float val = acc[m][n][r] + bv;
                if constexpr (OUTMODE == 0) {
                    ((bf16_t*)Cptr)[(size_t)rowg * DIM + colg] = (bf16_t)val;
                } else if constexpr (OUTMODE == 1) {
                    if (route[rowg] == 0) val = xfeat[(size_t)rowg * DIM + colg];
                    ((float*)Cptr)[(size_t)rowg * DIM + colg] = val;
                } else {  // OUTMODE == 2: Z = (route==2 ? H2 : bf16(x_feat))
                    if (route[rowg] != 2) val = xfeat[(size_t)rowg * DIM + colg];
                    ((bf16_t*)Cptr)[(size_t)rowg * DIM + colg] = (bf16_t)val;
                }
            }
        }
    }
}

// ---------------- launch ----------------

extern "C" void kernel_launch(void* const* d_in, const int* in_sizes, int n_in,
                              void* d_out, int out_size, void* d_ws, size_t ws_size,
                              hipStream_t stream) {
    (void)in_sizes; (void)n_in; (void)out_size; (void)ws_size;

    const float* x_feat  = (const float*)d_in[0];
    const float* x_angle = (const float*)d_in[1];
    const float* y_angle = (const float*)d_in[2];
    const float* Wp[4] = {(const float*)d_in[3], (const float*)d_in[5],
                          (const float*)d_in[7], (const float*)d_in[9]};
    const float* bp[4] = {(const float*)d_in[4], (const float*)d_in[6],
                          (const float*)d_in[8], (const float*)d_in[10]};

    // ws layout: route (256KB) | Wb (8MB bf16) | Hb (128MB bf16)  => ~136.5 MB
    char* ws = (char*)d_ws;
    int*    route = (int*)ws;
    bf16_t* Wb    = (bf16_t*)(ws + (1u << 18));
    bf16_t* Hb    = (bf16_t*)(ws + (1u << 18) + (1u << 23));
    // d_out (256MB f32) hosts two bf16 [N][DIM] scratch regions until the final write
    bf16_t* regA  = (bf16_t*)d_out;
    bf16_t* regB  = (bf16_t*)((char*)d_out + (size_t)N_ROWS * DIM * 2);

    route_kernel<<<N_ROWS / 256, 256, 0, stream>>>(x_angle, y_angle, route);
    for (int i = 0; i < 4; ++i)
        cvt_f32_bf16<<<(DIM * DIM / 8) / 256, 256, 0, stream>>>(Wp[i], Wb + (size_t)i * DIM * DIM);

    // G1: H1 = x_feat @ W1^T + b1          (f32 A, converted in staging) -> regA (bf16)
    gemm_bt<1, 0><<<4096, 256, 0, stream>>>(x_feat, Wb, bp[0], regA, nullptr, nullptr);
    // G2: Z = select(route==2, H1 @ W2^T + b2, bf16(x_feat))             -> regB (bf16)
    gemm_bt<0, 2><<<4096, 256, 0, stream>>>(regA, Wb + (size_t)1 * DIM * DIM, bp[1], regB, route, x_feat);
    // G3: H3 = Z @ W3^T + b3                                             -> Hb (ws, bf16)
    gemm_bt<0, 0><<<4096, 256, 0, stream>>>(regB, Wb + (size_t)2 * DIM * DIM, bp[2], Hb, nullptr, nullptr);
    // G4: out = select(route==0, x_feat, H3 @ W4^T + b4)                 -> d_out (f32)
    gemm_bt<0, 1><<<4096, 256, 0, stream>>>(Hb, Wb + (size_t)3 * DIM * DIM, bp[3], d_out, route, x_feat);
}